// Round 2
// baseline (75010.004 us; speedup 1.0000x reference)
//
#include <hip/hip_runtime.h>
#include <hip/hip_bf16.h>

#define B_   4096
#define T_   365
#define F_   16
#define H_   256
#define ROWS 64            // batch rows per block
#define NBLK (B_ / ROWS)   // 64 blocks
#define NKT  9             // K tiles of 32: 288 = 256 h + 16 x + 1 bias + 15 zero
#define SROW 296           // LDS row stride (shorts); 592B, 16B-aligned, bank-spread

typedef __attribute__((ext_vector_type(8))) short bf16x8;
typedef __attribute__((ext_vector_type(4))) float f32x4;

__device__ __forceinline__ short f2bf(float v) {        // fp32 -> bf16 RNE
  unsigned b = __float_as_uint(v);
  unsigned r = b + 0x7FFFu + ((b >> 16) & 1u);
  return (short)(r >> 16);
}
__device__ __forceinline__ float bf2f(short s) {
  return __uint_as_float(((unsigned)(unsigned short)s) << 16);
}
__device__ __forceinline__ float sigmoid_(float x) { return 1.0f / (1.0f + __expf(-x)); }
__device__ __forceinline__ float tanh_s(float x) {      // overflow-safe tanh
  float ax = fabsf(x);
  float t  = __expf(-2.0f * ax);
  float r  = (1.0f - t) / (1.0f + t);
  return x < 0.0f ? -r : r;
}

// ---------------------------------------------------------------------------
// prep: pack W into per-wave MFMA B-fragment order, bf16 hi/lo split.
// Layout: [qg(2)][kt(9)][qq(8)][g(4)][s(2)][lane(64)][j(8)] bf16
//   n = g*256 + qg*128 + qq*16 + (lane&15)   (gate-unit row of W)
//   k = kt*32 + (lane>>4)*8 + j              (depth; k=272 column = bias)
// One block per (qg,kt,qq,g,s), 512 threads write 512 consecutive shorts.
// ---------------------------------------------------------------------------
__global__ __launch_bounds__(512) void prep_kernel(
    const float* __restrict__ W_ih, const float* __restrict__ W_hh,
    const float* __restrict__ b_ih, const float* __restrict__ b_hh,
    short* __restrict__ Wpk) {
  const int bi = blockIdx.x;           // 0..1151
  const int s  = bi & 1;
  const int g  = (bi >> 1) & 3;
  const int qq = (bi >> 3) & 7;
  const int t3 = bi >> 6;              // qg*9 + kt
  const int kt = t3 % 9;
  const int qg = t3 / 9;
  const int lf = threadIdx.x >> 3;     // fragment lane 0..63
  const int j  = threadIdx.x & 7;

  const int n = g * 256 + qg * 128 + qq * 16 + (lf & 15);
  const int k = kt * 32 + (lf >> 4) * 8 + j;

  float v;
  if (k < 256)      v = W_hh[n * 256 + k];
  else if (k < 272) v = W_ih[n * 16 + (k - 256)];
  else if (k == 272) v = b_ih[n] + b_hh[n];   // bias via constant-1.0 column
  else              v = 0.0f;

  short hi = f2bf(v);
  short e  = hi;
  if (s == 1) e = f2bf(v - bf2f(hi));
  Wpk[(size_t)bi * 512 + threadIdx.x] = e;
}

// ---------------------------------------------------------------------------
// Persistent LSTM, MFMA path. 64 blocks x 512 threads (8 waves/CU, 2/SIMD).
// Wave (rt,qg): rowtile rt (16 rows), 32 col-tiles {g*16 + qg*8 + qq}.
// Thread holds C-frags acc[qq][g] (128 VGPR) + c-state c_[32].
// h kept in LDS pre-split as bf16 hi/lo planes; A-frags = direct ds_read_b128.
// 3-product split GEMM: acc += Ahi*Bhi + Ahi*Blo + Alo*Bhi.
// ---------------------------------------------------------------------------
__global__ __launch_bounds__(512, 2) void lstm_kernel(
    const float* __restrict__ w, const short* __restrict__ Wpk,
    const float* __restrict__ W_out, const float* __restrict__ b_out,
    float* __restrict__ out) {
  __shared__ short hsH[ROWS * SROW];
  __shared__ short hsL[ROWS * SROW];
  __shared__ float red[2 * ROWS * 2];   // head partials after in-wave shuffle

  const int tid  = threadIdx.x;
  const int lane = tid & 63;
  const int wv   = tid >> 6;
  const int rt   = wv & 3;            // rowtile 0..3
  const int qg   = wv >> 2;           // col-group 0..1
  const int c15  = tid & 15;
  const int q4   = (tid >> 4) & 3;
  const int b0   = blockIdx.x * ROWS;

  // ---- init LDS ----
  for (int i = tid; i < ROWS * SROW / 2; i += 512) {
    ((int*)hsH)[i] = 0;
    ((int*)hsL)[i] = 0;
  }
  __syncthreads();
  if (tid < ROWS) hsH[tid * SROW + 272] = (short)0x3F80;  // the 1.0 bias column
  const int xr0 = tid >> 4;           // 0..31
  const int xr1 = 32 + xr0;
  const int xf  = c15;
  {
    float xa = w[(size_t)(b0 + xr0) * (T_ * F_) + xf];
    float xb = w[(size_t)(b0 + xr1) * (T_ * F_) + xf];
    short ha = f2bf(xa), la = f2bf(xa - bf2f(ha));
    short hb = f2bf(xb), lb = f2bf(xb - bf2f(hb));
    hsH[xr0 * SROW + 256 + xf] = ha; hsL[xr0 * SROW + 256 + xf] = la;
    hsH[xr1 * SROW + 256 + xf] = hb; hsL[xr1 * SROW + 256 + xf] = lb;
  }
  __syncthreads();

  float c_[32];
#pragma unroll
  for (int i = 0; i < 32; ++i) c_[i] = 0.0f;

  const short* wbaseP  = Wpk + (size_t)qg * 294912 + lane * 8;  // per-wave frag stream
  const int    arowoff = (rt * 16 + c15) * SROW;

  for (int t = 0; t < T_; ++t) {
    // prefetch x_{t+1} (hides HBM latency under the MFMA phase)
    const int tt = (t + 1 < T_) ? (t + 1) : t;
    const float xa = w[(size_t)(b0 + xr0) * (T_ * F_) + (size_t)tt * F_ + xf];
    const float xb = w[(size_t)(b0 + xr1) * (T_ * F_) + (size_t)tt * F_ + xf];

    f32x4 acc[8][4];
#pragma unroll
    for (int qq = 0; qq < 8; ++qq)
#pragma unroll
      for (int g = 0; g < 4; ++g) acc[qq][g] = (f32x4){0.f, 0.f, 0.f, 0.f};

#pragma unroll
    for (int kt = 0; kt < NKT; ++kt) {
      const bf16x8 ahi = *(const bf16x8*)&hsH[arowoff + kt * 32 + q4 * 8];
      const bf16x8 alo = *(const bf16x8*)&hsL[arowoff + kt * 32 + q4 * 8];
#pragma unroll
      for (int qq = 0; qq < 8; ++qq) {
#pragma unroll
        for (int g = 0; g < 4; ++g) {
          const short* bp = wbaseP + ((kt * 8 + qq) * 4 + g) * 1024;
          const bf16x8 bhi = *(const bf16x8*)bp;
          const bf16x8 blo = *(const bf16x8*)(bp + 512);
          acc[qq][g] = __builtin_amdgcn_mfma_f32_16x16x32_bf16(ahi, bhi, acc[qq][g], 0, 0, 0);
          acc[qq][g] = __builtin_amdgcn_mfma_f32_16x16x32_bf16(ahi, blo, acc[qq][g], 0, 0, 0);
          acc[qq][g] = __builtin_amdgcn_mfma_f32_16x16x32_bf16(alo, bhi, acc[qq][g], 0, 0, 0);
        }
      }
    }
    __syncthreads();   // all A-frag reads of h_t / x_t complete

    // ---- activations + state update (all thread-local) ----
#pragma unroll
    for (int qq = 0; qq < 8; ++qq) {
      const int u = (qg * 8 + qq) * 16 + c15;
#pragma unroll
      for (int r4 = 0; r4 < 4; ++r4) {
        const int row = rt * 16 + q4 * 4 + r4;
        const float ig = sigmoid_(acc[qq][0][r4]);
        const float fg = sigmoid_(acc[qq][1][r4]);
        const float gg = tanh_s (acc[qq][2][r4]);
        const float og = sigmoid_(acc[qq][3][r4]);
        const float cn = fg * c_[qq * 4 + r4] + ig * gg;
        c_[qq * 4 + r4] = cn;
        const float hn = og * tanh_s(cn);
        const short hh = f2bf(hn);
        const short hl = f2bf(hn - bf2f(hh));
        hsH[row * SROW + u] = hh;
        hsL[row * SROW + u] = hl;
      }
    }
    // stage x_{t+1}
    {
      short ha = f2bf(xa), la = f2bf(xa - bf2f(ha));
      short hb = f2bf(xb), lb = f2bf(xb - bf2f(hb));
      hsH[xr0 * SROW + 256 + xf] = ha; hsL[xr0 * SROW + 256 + xf] = la;
      hsH[xr1 * SROW + 256 + xf] = hb; hsL[xr1 * SROW + 256 + xf] = lb;
    }
    __syncthreads();
  }

  // ---- epilogue: h output + head (ELU -> Linear(H,2)) ----
  float p0[4] = {0, 0, 0, 0}, p1[4] = {0, 0, 0, 0};
#pragma unroll
  for (int qq = 0; qq < 8; ++qq) {
    const int u = (qg * 8 + qq) * 16 + c15;
    const float w0 = W_out[u];
    const float w1 = W_out[H_ + u];
#pragma unroll
    for (int r4 = 0; r4 < 4; ++r4) {
      const int row = rt * 16 + q4 * 4 + r4;
      const float h = bf2f(hsH[row * SROW + u]) + bf2f(hsL[row * SROW + u]);
      out[8192 + (size_t)(b0 + row) * H_ + u] = h;
      const float e = h > 0.0f ? h : (__expf(h) - 1.0f);
      p0[r4] += e * w0;
      p1[r4] += e * w1;
    }
  }
  // reduce the 16 lanes (c15) of each quarter-wave via shuffle, then 2 qg-waves via LDS
#pragma unroll
  for (int r4 = 0; r4 < 4; ++r4) {
    float s0 = p0[r4], s1 = p1[r4];
#pragma unroll
    for (int d = 1; d < 16; d <<= 1) {
      s0 += __shfl_xor(s0, d, 64);
      s1 += __shfl_xor(s1, d, 64);
    }
    if (c15 == 0) {
      const int row = rt * 16 + q4 * 4 + r4;
      if (qg == 0) { red[(0 * ROWS + row) * 2 + 0] = s0; red[(1 * ROWS + row) * 2 + 0] = s1; }
      else         { red[(0 * ROWS + row) * 2 + 1] = s0; red[(1 * ROWS + row) * 2 + 1] = s1; }
    }
  }
  __syncthreads();
  if (tid < 2 * ROWS) {
    const int row = tid >> 1, o = tid & 1;
    const float s = b_out[o] + red[(o * ROWS + row) * 2 + 0] + red[(o * ROWS + row) * 2 + 1];
    out[(size_t)o * B_ + b0 + row] = s;
  }
}

extern "C" void kernel_launch(void* const* d_in, const int* in_sizes, int n_in,
                              void* d_out, int out_size, void* d_ws, size_t ws_size,
                              hipStream_t stream) {
  const float* w     = (const float*)d_in[0];
  const float* W_ih  = (const float*)d_in[1];
  const float* W_hh  = (const float*)d_in[2];
  const float* b_ih  = (const float*)d_in[3];
  const float* b_hh  = (const float*)d_in[4];
  const float* W_out = (const float*)d_in[5];
  const float* b_out = (const float*)d_in[6];
  float* out = (float*)d_out;
  short* Wpk = (short*)d_ws;   // 1,179,648 bytes of packed hi/lo weight fragments

  hipLaunchKernelGGL(prep_kernel, dim3(1152), dim3(512), 0, stream,
                     W_ih, W_hh, b_ih, b_hh, Wpk);
  hipLaunchKernelGGL(lstm_kernel, dim3(NBLK), dim3(512), 0, stream,
                     w, Wpk, W_out, b_out, out);
}

// Round 3
// 11505.371 us; speedup vs baseline: 6.5196x; 6.5196x over previous
//
#include <hip/hip_runtime.h>
#include <hip/hip_bf16.h>

#define B_   4096
#define T_   365
#define F_   16
#define H_   256
#define ROWS 32
#define NBLK (B_ / ROWS)     // 128 blocks
#define NKT  9               // K tiles of 32: 288 = 256 h + 16 x + 1 bias + 15 zero

typedef __attribute__((ext_vector_type(8))) short bf16x8;
typedef __attribute__((ext_vector_type(4))) float f32x4;

__device__ __forceinline__ short f2bf(float v) {        // fp32 -> bf16 RNE
  unsigned b = __float_as_uint(v);
  unsigned r = b + 0x7FFFu + ((b >> 16) & 1u);
  return (short)(r >> 16);
}
__device__ __forceinline__ float bf2f(short s) {
  return __uint_as_float(((unsigned)(unsigned short)s) << 16);
}
__device__ __forceinline__ float sigmoid_(float x) { return 1.0f / (1.0f + __expf(-x)); }
__device__ __forceinline__ float tanh_s(float x) {      // overflow-safe tanh
  float ax = fabsf(x);
  float t  = __expf(-2.0f * ax);
  float r  = (1.0f - t) / (1.0f + t);
  return x < 0.0f ? -r : r;
}

// ---------------------------------------------------------------------------
// prep: pack W into per-wave B-fragment streams, bf16 hi/lo.
// Frag fi = ((w*9 + kt)*8 + qq)*2 + s, 512 shorts each:
//   n = (qq>>1)*256 + w*32 + (qq&1)*16 + (lane&15)   (gate-row of W)
//   k = kt*32 + (lane>>4)*8 + j                      (k=272 col = bias)
// ---------------------------------------------------------------------------
__global__ __launch_bounds__(512) void prep_kernel(
    const float* __restrict__ W_ih, const float* __restrict__ W_hh,
    const float* __restrict__ b_ih, const float* __restrict__ b_hh,
    short* __restrict__ Wpk) {
  const int fi = blockIdx.x;          // 0..1151
  const int s  = fi & 1;
  const int t1 = fi >> 1;
  const int qq = t1 & 7;
  const int t2 = t1 >> 3;             // w*9 + kt
  const int kt = t2 % 9;
  const int w8 = t2 / 9;
  const int lf = threadIdx.x >> 3;    // fragment lane 0..63
  const int j  = threadIdx.x & 7;

  const int n = (qq >> 1) * 256 + w8 * 32 + (qq & 1) * 16 + (lf & 15);
  const int k = kt * 32 + (lf >> 4) * 8 + j;

  float v;
  if (k < 256)       v = W_hh[n * 256 + k];
  else if (k < 272)  v = W_ih[n * 16 + (k - 256)];
  else if (k == 272) v = b_ih[n] + b_hh[n];
  else               v = 0.0f;

  short hi = f2bf(v);
  short e  = hi;
  if (s == 1) e = f2bf(v - bf2f(hi));
  Wpk[(size_t)fi * 512 + threadIdx.x] = e;
}

// ---------------------------------------------------------------------------
// Persistent LSTM. 128 blocks x 512 threads (8 waves, 2/SIMD).
// Wave w owns units [w*32, w*32+32): col-tiles qq = g*2+half.
// A (h hi/lo + x + bias) lives in LDS in MFMA-FRAGMENT ORDER [rt][kt][lane][j]
//   -> ds_read_b128 at lane*16 is linear, conflict-free.
// B streamed global->VGPR, double-buffered one half-kt (8 frags) ahead:
//   24 MFMAs (~465 cyc) per stage cover L2 latency.
// ---------------------------------------------------------------------------
__global__ __launch_bounds__(512, 2) void lstm_kernel(
    const float* __restrict__ w, const short* __restrict__ Wpk,
    const float* __restrict__ W_out, const float* __restrict__ b_out,
    float* __restrict__ out) {
  __shared__ short aH[2 * NKT * 512];   // [rt][kt][lane][j]  (18 KB)
  __shared__ short aL[2 * NKT * 512];
  __shared__ float red[ROWS * 2];

  const int tid  = threadIdx.x;
  const int lane = tid & 63;
  const int wv   = tid >> 6;          // wave 0..7
  const int c15  = lane & 15;
  const int q4   = lane >> 4;         // 0..3
  const int b0   = blockIdx.x * ROWS;

  // ---- zero A planes, then seed bias + x(t=0) ----
  for (int i = tid; i < 2 * NKT * 512 / 2; i += 512) {
    ((int*)aH)[i] = 0;
    ((int*)aL)[i] = 0;
  }
  __syncthreads();
  if (tid < 32) {   // bias column k=272 -> kt=8, lane=(row&15)+32, j=0
    const int row = tid;
    aH[((row >> 4) * NKT + 8) * 512 + ((row & 15) + 32) * 8] = (short)0x3F80;
  }
  const int xrow = tid >> 4, xf = tid & 15;   // x staging: 32 rows x 16 feats
  const int ax = ((xrow >> 4) * NKT + 8) * 512 + ((xrow & 15) + 16 * (xf >> 3)) * 8 + (xf & 7);
  {
    const float xv = w[(size_t)(b0 + xrow) * (T_ * F_) + xf];
    const short xh = f2bf(xv), xl = f2bf(xv - bf2f(xh));
    aH[ax] = xh; aL[ax] = xl;
  }
  __syncthreads();

  float c_[16];
#pragma unroll
  for (int i = 0; i < 16; ++i) c_[i] = 0.0f;

  // per-wave B stream: frag(kt,qq,s) at wbase + ((kt*8+qq)*2+s)*512 + lane*8
  const short* wbase = Wpk + (size_t)wv * (NKT * 8 * 2 * 512) + lane * 8;

  for (int t = 0; t < T_; ++t) {
    // prefetch x_{t+1} (consumed after the MFMA phase)
    const int tt = (t + 1 < T_) ? (t + 1) : t;
    const float xnext = w[(size_t)(b0 + xrow) * (T_ * F_) + (size_t)tt * F_ + xf];

    f32x4 acc[2][8];
#pragma unroll
    for (int rt = 0; rt < 2; ++rt)
#pragma unroll
      for (int qq = 0; qq < 8; ++qq) acc[rt][qq] = (f32x4){0.f, 0.f, 0.f, 0.f};

    bf16x8 AH[2][2], AL[2][2];   // [kt&1][rt]
    bf16x8 BH[2][4], BL[2][4];   // [st&1][qi]

    // preload A(kt=0), B(stage 0)
#pragma unroll
    for (int rt = 0; rt < 2; ++rt) {
      AH[0][rt] = *(const bf16x8*)&aH[(rt * NKT + 0) * 512 + lane * 8];
      AL[0][rt] = *(const bf16x8*)&aL[(rt * NKT + 0) * 512 + lane * 8];
    }
#pragma unroll
    for (int qi = 0; qi < 4; ++qi) {
      BH[0][qi] = *(const bf16x8*)(wbase + ((0 * 8 + qi) * 2 + 0) * 512);
      BL[0][qi] = *(const bf16x8*)(wbase + ((0 * 8 + qi) * 2 + 1) * 512);
    }

    // 18 stages of 24 MFMAs (kt = st>>1, col-half p = st&1)
#pragma unroll
    for (int st = 0; st < 18; ++st) {
      const int kt = st >> 1;
      const int p  = st & 1;
      const int nst = st + 1;
      if (nst < 18) {                     // issue next stage's B loads now
        const int nkt = nst >> 1, np = nst & 1;
#pragma unroll
        for (int qi = 0; qi < 4; ++qi) {
          BH[nst & 1][qi] = *(const bf16x8*)(wbase + ((nkt * 8 + np * 4 + qi) * 2 + 0) * 512);
          BL[nst & 1][qi] = *(const bf16x8*)(wbase + ((nkt * 8 + np * 4 + qi) * 2 + 1) * 512);
        }
        if (np == 0) {                    // new kt -> fetch its A frags
#pragma unroll
          for (int rt = 0; rt < 2; ++rt) {
            AH[nkt & 1][rt] = *(const bf16x8*)&aH[(rt * NKT + nkt) * 512 + lane * 8];
            AL[nkt & 1][rt] = *(const bf16x8*)&aL[(rt * NKT + nkt) * 512 + lane * 8];
          }
        }
      }
      // product-major order: consecutive MFMAs hit independent accumulators
#pragma unroll
      for (int prod = 0; prod < 3; ++prod)
#pragma unroll
        for (int qi = 0; qi < 4; ++qi)
#pragma unroll
          for (int rt = 0; rt < 2; ++rt) {
            const int qq = p * 4 + qi;
            const bf16x8 a = (prod == 2) ? AL[kt & 1][rt] : AH[kt & 1][rt];
            const bf16x8 b = (prod == 1) ? BL[st & 1][qi] : BH[st & 1][qi];
            acc[rt][qq] = __builtin_amdgcn_mfma_f32_16x16x32_bf16(a, b, acc[rt][qq], 0, 0, 0);
          }
    }
    __syncthreads();   // all A reads done before rewriting h

    // ---- pointwise: i,f,g,o -> c,h (thread-local), write h hi/lo to A-frags ----
    const short xh = f2bf(xnext), xl = f2bf(xnext - bf2f(xh));
#pragma unroll
    for (int half = 0; half < 2; ++half) {
      const int u = wv * 32 + half * 16 + c15;
#pragma unroll
      for (int rt = 0; rt < 2; ++rt)
#pragma unroll
        for (int r = 0; r < 4; ++r) {
          const int ci = (half * 2 + rt) * 4 + r;
          const float ig = sigmoid_(acc[rt][0 + half][r]);
          const float fg = sigmoid_(acc[rt][2 + half][r]);
          const float gg = tanh_s (acc[rt][4 + half][r]);
          const float og = sigmoid_(acc[rt][6 + half][r]);
          const float cn = fg * c_[ci] + ig * gg;
          c_[ci] = cn;
          const float hn = og * tanh_s(cn);
          const int row = rt * 16 + q4 * 4 + r;
          const int ai = ((row >> 4) * NKT + (u >> 5)) * 512 +
                         ((row & 15) + 16 * ((u & 31) >> 3)) * 8 + (u & 7);
          const short hh = f2bf(hn);
          aH[ai] = hh;
          aL[ai] = f2bf(hn - bf2f(hh));
        }
    }
    aH[ax] = xh; aL[ax] = xl;   // stage x_{t+1}
    __syncthreads();
  }

  // ---- epilogue: h out + head (ELU -> Linear(H,2)) ----
  if (tid < ROWS * 2) red[tid] = 0.0f;
  __syncthreads();
  float p0[8], p1[8];
#pragma unroll
  for (int i = 0; i < 8; ++i) { p0[i] = 0.0f; p1[i] = 0.0f; }
#pragma unroll
  for (int half = 0; half < 2; ++half) {
    const int u = wv * 32 + half * 16 + c15;
    const float w0 = W_out[u], w1 = W_out[H_ + u];
#pragma unroll
    for (int rt = 0; rt < 2; ++rt)
#pragma unroll
      for (int r = 0; r < 4; ++r) {
        const int row = rt * 16 + q4 * 4 + r;
        const int ai = ((row >> 4) * NKT + (u >> 5)) * 512 +
                       ((row & 15) + 16 * ((u & 31) >> 3)) * 8 + (u & 7);
        const float h = bf2f(aH[ai]) + bf2f(aL[ai]);
        out[8192 + (size_t)(b0 + row) * H_ + u] = h;
        const float e = h > 0.0f ? h : (__expf(h) - 1.0f);
        p0[rt * 4 + r] += e * w0;
        p1[rt * 4 + r] += e * w1;
      }
  }
#pragma unroll
  for (int i = 0; i < 8; ++i) {
    float s0 = p0[i], s1 = p1[i];
#pragma unroll
    for (int d = 1; d < 16; d <<= 1) {
      s0 += __shfl_xor(s0, d, 64);
      s1 += __shfl_xor(s1, d, 64);
    }
    if (c15 == 0) {
      const int row = (i >> 2) * 16 + q4 * 4 + (i & 3);   // i = rt*4+r
      atomicAdd(&red[row * 2 + 0], s0);
      atomicAdd(&red[row * 2 + 1], s1);
    }
  }
  __syncthreads();
  if (tid < ROWS * 2) {
    const int row = tid >> 1, o = tid & 1;
    out[(size_t)o * B_ + b0 + row] = b_out[o] + red[row * 2 + o];
  }
}

extern "C" void kernel_launch(void* const* d_in, const int* in_sizes, int n_in,
                              void* d_out, int out_size, void* d_ws, size_t ws_size,
                              hipStream_t stream) {
  const float* w     = (const float*)d_in[0];
  const float* W_ih  = (const float*)d_in[1];
  const float* W_hh  = (const float*)d_in[2];
  const float* b_ih  = (const float*)d_in[3];
  const float* b_hh  = (const float*)d_in[4];
  const float* W_out = (const float*)d_in[5];
  const float* b_out = (const float*)d_in[6];
  float* out = (float*)d_out;
  short* Wpk = (short*)d_ws;   // 1,179,648 B packed hi/lo weight fragments

  hipLaunchKernelGGL(prep_kernel, dim3(1152), dim3(512), 0, stream,
                     W_ih, W_hh, b_ih, b_hh, Wpk);
  hipLaunchKernelGGL(lstm_kernel, dim3(NBLK), dim3(512), 0, stream,
                     w, Wpk, W_out, b_out, out);
}